// Round 6
// baseline (593.486 us; speedup 1.0000x reference)
//
#include <hip/hip_runtime.h>
#include <stdint.h>

#define NN 100000
#define EE 1600000
#define DD 64
#define NB 391   // ceil(NN/256)

// ---------------- CSR build via linked lists (single atomic per edge) ----------------

__global__ void build_kernel(const int* __restrict__ dst,
                             int* __restrict__ head, int* __restrict__ next) {
    int e = blockIdx.x * blockDim.x + threadIdx.x;
    if (e < EE) {
        next[e] = atomicExch(&head[dst[e]], e);   // only atomic in the build
    }
}

// 1 thread/node: chain length -> cnt (no atomics)
__global__ void count_walk(const int* __restrict__ head, const int* __restrict__ next,
                           int* __restrict__ cnt) {
    int i = blockIdx.x * 256 + threadIdx.x;
    if (i >= NN) return;
    int c = 0;
    for (int p = head[i]; p >= 0; p = next[p]) c++;
    cnt[i] = c;
}

__global__ void scan1(const int* __restrict__ cnt, int* __restrict__ partial) {
    __shared__ int s[256];
    int i = blockIdx.x * 256 + threadIdx.x;
    int v = (i < NN) ? cnt[i] : 0;
    s[threadIdx.x] = v;
    __syncthreads();
    for (int off = 128; off > 0; off >>= 1) {
        if (threadIdx.x < off) s[threadIdx.x] += s[threadIdx.x + off];
        __syncthreads();
    }
    if (threadIdx.x == 0) partial[blockIdx.x] = s[0];
}

__global__ void scan2(int* __restrict__ partial) {
    __shared__ int s[512];
    int t = threadIdx.x;
    int v = (t < NB) ? partial[t] : 0;
    s[t] = v;
    __syncthreads();
    for (int off = 1; off < 512; off <<= 1) {
        int add = (t >= off) ? s[t - off] : 0;
        __syncthreads();
        s[t] += add;
        __syncthreads();
    }
    if (t < NB) partial[t] = s[t] - v;  // exclusive
}

__global__ void scan3(const int* __restrict__ cnt, const int* __restrict__ partial,
                      int* __restrict__ offsets) {
    __shared__ int s[256];
    int t = threadIdx.x;
    int i = blockIdx.x * 256 + t;
    int v = (i < NN) ? cnt[i] : 0;
    s[t] = v;
    __syncthreads();
    for (int off = 1; off < 256; off <<= 1) {
        int add = (t >= off) ? s[t - off] : 0;
        __syncthreads();
        s[t] += add;
        __syncthreads();
    }
    int excl = s[t] - v + partial[blockIdx.x];
    if (i < NN) {
        offsets[i] = excl;
        if (i == NN - 1) offsets[NN] = excl + v;
    }
}

// 1 thread per node: walk linked list, write csr contiguously (full-line writes)
__global__ void walk_kernel(const int* __restrict__ head, const int* __restrict__ next,
                            const int* __restrict__ srcA, const int* __restrict__ offsets,
                            int* __restrict__ csr) {
    int i = blockIdx.x * 256 + threadIdx.x;
    if (i >= NN) return;
    int p = head[i];
    int w = offsets[i];
    while (p >= 0) {
        csr[w++] = srcA[p];
        p = next[p];
    }
}

// ---------------- fused 3-way GEMM: Xl = h@Wl+bl, XRS = [h@Wr+br | h@Ws+bs] ----------------
// 512 threads, 64 rows/block. Weights transposed in LDS (WT[c][k], pad 68 -> b128-aligned,
// lanes spread over all 32 banks). h read direct from global: wave-uniform address ->
// L1 broadcast, no LDS tile, no second barrier.

__global__ __launch_bounds__(512) void gemm_fused(
    const float* __restrict__ hin,
    const float* __restrict__ Wl, const float* __restrict__ Wr, const float* __restrict__ Ws,
    const float* __restrict__ bl, const float* __restrict__ br, const float* __restrict__ bs,
    float* __restrict__ Xl, float* __restrict__ XRS) {
    __shared__ float WT[3][64][68];
    __shared__ float bias[192];
    int t = threadIdx.x;
    for (int idx = t; idx < 4096; idx += 512) {
        int k = idx >> 6, c = idx & 63;
        WT[0][c][k] = Wl[idx];
        WT[1][c][k] = Wr[idx];
        WT[2][c][k] = Ws[idx];
    }
    if (t < 192) bias[t] = (t < 64) ? bl[t] : (t < 128 ? br[t - 64] : bs[t - 128]);
    __syncthreads();

    int c  = t & 63;
    int rg = t >> 6;  // 0..7 -> rows rg*8 .. rg*8+7
    int row0 = blockIdx.x * 64 + rg * 8;

    int rowS[8];
#pragma unroll
    for (int rr = 0; rr < 8; rr++) {
        int r = row0 + rr;
        rowS[rr] = (r < NN) ? r : (NN - 1);
    }

    float acc0[8], acc1[8], acc2[8];
#pragma unroll
    for (int r = 0; r < 8; r++) { acc0[r] = 0.f; acc1[r] = 0.f; acc2[r] = 0.f; }

#pragma unroll 2
    for (int k0 = 0; k0 < 64; k0 += 4) {
        float4 w0 = *(const float4*)&WT[0][c][k0];
        float4 w1 = *(const float4*)&WT[1][c][k0];
        float4 w2 = *(const float4*)&WT[2][c][k0];
#pragma unroll
        for (int rr = 0; rr < 8; rr++) {
            float4 hv = *(const float4*)&hin[(size_t)rowS[rr] * 64 + k0];  // wave-uniform -> L1 broadcast
            acc0[rr] += hv.x * w0.x + hv.y * w0.y + hv.z * w0.z + hv.w * w0.w;
            acc1[rr] += hv.x * w1.x + hv.y * w1.y + hv.z * w1.z + hv.w * w1.w;
            acc2[rr] += hv.x * w2.x + hv.y * w2.y + hv.z * w2.z + hv.w * w2.w;
        }
    }
    float b0 = bias[c], b1 = bias[64 + c], b2 = bias[128 + c];
#pragma unroll
    for (int rr = 0; rr < 8; rr++) {
        int row = row0 + rr;
        if (row < NN) {
            Xl[(size_t)row * 64 + c]        = acc0[rr] + b0;
            XRS[(size_t)row * 128 + c]      = acc1[rr] + b1;
            XRS[(size_t)row * 128 + 64 + c] = acc2[rr] + b2;
        }
    }
}

// ---------------- per-node attention aggregation ----------------
// One wave per dst node; 4 edges in parallel, 16 lanes per edge.
// Lane l owns features 4*(l&15) .. 4*(l&15)+3 of its edge's xl as a float4.

__device__ __forceinline__ float group_sum16(float t) {
    t += __int_as_float(__builtin_amdgcn_update_dpp(0, __float_as_int(t), 0xB1, 0xF, 0xF, true));   // xor1
    t += __int_as_float(__builtin_amdgcn_update_dpp(0, __float_as_int(t), 0x4E, 0xF, 0xF, true));   // xor2
    t += __int_as_float(__builtin_amdgcn_update_dpp(0, __float_as_int(t), 0x141, 0xF, 0xF, true));  // row_half_mirror ~ xor4
    t += __int_as_float(__builtin_amdgcn_update_dpp(0, __float_as_int(t), 0x140, 0xF, 0xF, true));  // row_mirror ~ xor8
    return t;
}

__device__ __forceinline__ float lrelu(float v) {
    return (v > 0.f) ? v : 0.2f * v;
}

__global__ __launch_bounds__(256) void node_kernel(
    const float* __restrict__ Xl, const float* __restrict__ XRS,
    const int* __restrict__ offsets, const int* __restrict__ csr,
    const float* __restrict__ att, const float* __restrict__ bg,
    float* __restrict__ hout, int do_relu,
    const float* __restrict__ Wout, const float* __restrict__ bout,
    float* __restrict__ outp, int do_out) {
    int lane = threadIdx.x & 63;
    int wid  = threadIdx.x >> 6;
    int i = blockIdx.x * 4 + wid;
    if (i >= NN) return;
    int sub = lane & 15;   // feature-quad index: features 4*sub..4*sub+3
    int grp = lane >> 4;   // edge slot 0..3

    float4 xr4  = *(const float4*)&XRS[(size_t)i * 128 + sub * 4];
    float4 att4 = *(const float4*)&att[sub * 4];

    float aggx = 0.f, aggy = 0.f, aggz = 0.f, aggw = 0.f;
    float denom = 0.f;
    int beg = offsets[i], end = offsets[i + 1];

    for (int j0 = beg; j0 < end; j0 += 8) {
        int jA = j0 + grp, jB = j0 + grp + 4;
        bool vA = jA < end, vB = jB < end;
        int sA = csr[vA ? jA : beg];
        int sB = csr[vB ? jB : beg];
        float4 xA = *(const float4*)&Xl[(size_t)sA * 64 + sub * 4];
        float4 xB = *(const float4*)&Xl[(size_t)sB * 64 + sub * 4];

        float tA = lrelu(xA.x + xr4.x) * att4.x + lrelu(xA.y + xr4.y) * att4.y
                 + lrelu(xA.z + xr4.z) * att4.z + lrelu(xA.w + xr4.w) * att4.w;
        float tB = lrelu(xB.x + xr4.x) * att4.x + lrelu(xB.y + xr4.y) * att4.y
                 + lrelu(xB.z + xr4.z) * att4.z + lrelu(xB.w + xr4.w) * att4.w;
        tA = group_sum16(tA);
        tB = group_sum16(tB);
        float aA = vA ? __expf(tA) : 0.f;
        float aB = vB ? __expf(tB) : 0.f;

        aggx += aA * xA.x + aB * xB.x;
        aggy += aA * xA.y + aB * xB.y;
        aggz += aA * xA.z + aB * xB.z;
        aggw += aA * xA.w + aB * xB.w;
        denom += aA + aB;
    }

    // combine the 4 edge groups (once per node)
#pragma unroll
    for (int m = 16; m <= 32; m <<= 1) {
        aggx  += __shfl_xor(aggx, m, 64);
        aggy  += __shfl_xor(aggy, m, 64);
        aggz  += __shfl_xor(aggz, m, 64);
        aggw  += __shfl_xor(aggw, m, 64);
        denom += __shfl_xor(denom, m, 64);
    }

    float inv = (denom > 0.f) ? (1.0f / denom) : 0.f;
    float4 sk4 = *(const float4*)&XRS[(size_t)i * 128 + 64 + sub * 4];
    float4 bg4 = *(const float4*)&bg[sub * 4];
    float4 res;
    res.x = aggx * inv + bg4.x + sk4.x;
    res.y = aggy * inv + bg4.y + sk4.y;
    res.z = aggz * inv + bg4.z + sk4.z;
    res.w = aggw * inv + bg4.w + sk4.w;
    if (do_relu) {
        res.x = fmaxf(res.x, 0.f); res.y = fmaxf(res.y, 0.f);
        res.z = fmaxf(res.z, 0.f); res.w = fmaxf(res.w, 0.f);
    }
    if (do_out) {
        // fused final projection: out[i][j] = sum_f h[f] * Wout[f][j] + bout[j]
        float4 w01 = *(const float4*)&Wout[8 * sub];       // W[4s+0][0..1], W[4s+1][0..1]
        float4 w23 = *(const float4*)&Wout[8 * sub + 4];   // W[4s+2][0..1], W[4s+3][0..1]
        float o0 = res.x * w01.x + res.y * w01.z + res.z * w23.x + res.w * w23.z;
        float o1 = res.x * w01.y + res.y * w01.w + res.z * w23.y + res.w * w23.w;
        o0 = group_sum16(o0);
        o1 = group_sum16(o1);
        if (lane == 0) {
            outp[(size_t)i * 2 + 0] = o0 + bout[0];
            outp[(size_t)i * 2 + 1] = o1 + bout[1];
        }
    } else {
        if (grp == 0) *(float4*)&hout[(size_t)i * 64 + sub * 4] = res;
    }
}

// ---------------- launch ----------------

extern "C" void kernel_launch(void* const* d_in, const int* in_sizes, int n_in,
                              void* d_out, int out_size, void* d_ws, size_t ws_size,
                              hipStream_t stream) {
    const float* x    = (const float*)d_in[0];
    const int*   ei   = (const int*)d_in[1];   // [2][E]: row0=src, row1=dst
    const float* Wl   = (const float*)d_in[2];
    const float* bl   = (const float*)d_in[3];
    const float* Wr   = (const float*)d_in[4];
    const float* br   = (const float*)d_in[5];
    const float* att  = (const float*)d_in[6];
    const float* bg   = (const float*)d_in[7];
    const float* Ws   = (const float*)d_in[8];
    const float* bs   = (const float*)d_in[9];
    const float* Wout = (const float*)d_in[10];
    const float* bout = (const float*)d_in[11];
    float* out = (float*)d_out;

    size_t off = 0;
    char* base = (char*)d_ws;
    auto alloc = [&](size_t bytes) -> void* {
        void* p = base + off;
        off += (bytes + 255) & ~(size_t)255;
        return p;
    };
    float* Xl     = (float*)alloc((size_t)NN * 64 * 4);
    float* XRS    = (float*)alloc((size_t)NN * 128 * 4);
    float* h      = (float*)alloc((size_t)NN * 64 * 4);
    int*   cnt    = (int*)alloc((size_t)NN * 4);
    int*   headA  = (int*)alloc((size_t)NN * 4);
    int*   nextA  = (int*)alloc((size_t)EE * 4);
    int*   offs   = (int*)alloc((size_t)(NN + 1) * 4);
    int*   csr    = (int*)alloc((size_t)EE * 4);
    int*   part   = (int*)alloc(512 * 4);

    const int* src = ei;
    const int* dst = ei + EE;

    hipMemsetAsync(headA, 0xFF, (size_t)NN * 4, stream);   // -1
    build_kernel<<<(EE + 255) / 256, 256, 0, stream>>>(dst, headA, nextA);
    count_walk<<<NB, 256, 0, stream>>>(headA, nextA, cnt);
    scan1<<<NB, 256, 0, stream>>>(cnt, part);
    scan2<<<1, 512, 0, stream>>>(part);
    scan3<<<NB, 256, 0, stream>>>(cnt, part, offs);
    walk_kernel<<<NB, 256, 0, stream>>>(headA, nextA, src, offs, csr);

    const float* hin = x;
    for (int L = 0; L < 3; L++) {
        gemm_fused<<<(NN + 63) / 64, 512, 0, stream>>>(
            hin, Wl + L * 4096, Wr + L * 4096, Ws + L * 4096,
            bl + L * 64, br + L * 64, bs + L * 64, Xl, XRS);
        node_kernel<<<NN / 4, 256, 0, stream>>>(
            Xl, XRS, offs, csr, att + L * 64, bg + L * 64, h, (L < 2) ? 1 : 0,
            Wout, bout, out, (L == 2) ? 1 : 0);
        hin = h;
    }
}